// Round 1
// baseline (106.973 us; speedup 1.0000x reference)
//
#include <hip/hip_runtime.h>

// Problem geometry (fixed by the reference):
//   X: [512, 3, 384, 192] f32, W: [4, 3] f32, out: [128, 3, 384, 192] f32
//   out[g,c,h,w] = sum_s X[4g+s,c,h,w] * W[s,c]
constexpr int HW4    = (384 * 192) / 4;  // float4s per (b,c) plane = 18432
constexpr int CHW4   = 3 * HW4;          // float4s per image       = 55296
constexpr int PLANES = 128 * 3;          // output planes           = 384
constexpr int TPB    = 256;
constexpr int ITER   = 4;                // float4 outputs per thread
// grid.x = HW4 / (TPB*ITER) = 18432 / 1024 = 18  (exact, no tail)

__global__ __launch_bounds__(TPB) void wsum_kernel(
    const float4* __restrict__ X, const float* __restrict__ W,
    float4* __restrict__ O)
{
    const int plane = blockIdx.y;      // g*3 + c  (wave-uniform)
    const int c = plane % 3;
    const int g = plane / 3;

    // Wave-uniform weight loads -> scalar loads, broadcast.
    const float w0 = W[0 + c];
    const float w1 = W[3 + c];
    const float w2 = W[6 + c];
    const float w3 = W[9 + c];

    const int base_in  = (g * 4) * CHW4 + c * HW4;  // sample 0 plane, in float4s
    const int base_out = plane * HW4;

    int hw = blockIdx.x * (TPB * ITER) + threadIdx.x;
#pragma unroll
    for (int it = 0; it < ITER; ++it, hw += TPB) {
        const float4 a = X[base_in + 0 * CHW4 + hw];
        const float4 b = X[base_in + 1 * CHW4 + hw];
        const float4 e = X[base_in + 2 * CHW4 + hw];
        const float4 d = X[base_in + 3 * CHW4 + hw];
        float4 r;
        r.x = fmaf(d.x, w3, fmaf(e.x, w2, fmaf(b.x, w1, a.x * w0)));
        r.y = fmaf(d.y, w3, fmaf(e.y, w2, fmaf(b.y, w1, a.y * w0)));
        r.z = fmaf(d.z, w3, fmaf(e.z, w2, fmaf(b.z, w1, a.z * w0)));
        r.w = fmaf(d.w, w3, fmaf(e.w, w2, fmaf(b.w, w1, a.w * w0)));
        O[base_out + hw] = r;
    }
}

extern "C" void kernel_launch(void* const* d_in, const int* in_sizes, int n_in,
                              void* d_out, int out_size, void* d_ws, size_t ws_size,
                              hipStream_t stream) {
    const float4* X = (const float4*)d_in[0];
    const float*  W = (const float*)d_in[1];
    float4*       O = (float4*)d_out;

    dim3 grid(HW4 / (TPB * ITER), PLANES);  // (18, 384)
    wsum_kernel<<<grid, TPB, 0, stream>>>(X, W, O);
}

// Round 3
// 93.843 us; speedup vs baseline: 1.1399x; 1.1399x over previous
//
#include <hip/hip_runtime.h>

// Problem geometry (fixed by the reference):
//   X: [512, 3, 384, 192] f32, W: [4, 3] f32, out: [128, 3, 384, 192] f32
//   out[g,c,h,w] = sum_s X[4g+s,c,h,w] * W[s,c]
// Pure streaming op: each input elem read once, each output written once.
// Nontemporal loads/stores (nt flag) to skip cache allocation — zero reuse.
// NOTE: __builtin_nontemporal_* needs a native clang vector type, not
// HIP_vector_type — hence the ext_vector_type typedef.
typedef float f32x4 __attribute__((ext_vector_type(4)));

constexpr int HW4    = (384 * 192) / 4;  // float4s per (b,c) plane = 18432
constexpr int CHW4   = 3 * HW4;          // float4s per image       = 55296
constexpr int PLANES = 128 * 3;          // output planes           = 384
constexpr int TPB    = 256;
constexpr int ITER   = 4;                // float4 outputs per thread
// grid.x = HW4 / (TPB*ITER) = 18432 / 1024 = 18  (exact, no tail)

__global__ __launch_bounds__(TPB) void wsum_kernel(
    const f32x4* __restrict__ X, const float* __restrict__ W,
    f32x4* __restrict__ O)
{
    const int plane = blockIdx.y;      // g*3 + c  (wave-uniform)
    const int c = plane % 3;
    const int g = plane / 3;

    // Wave-uniform weight loads -> scalar loads, broadcast.
    const float w0 = W[0 + c];
    const float w1 = W[3 + c];
    const float w2 = W[6 + c];
    const float w3 = W[9 + c];

    const int base_in  = (g * 4) * CHW4 + c * HW4;  // sample 0 plane, in f32x4s
    const int base_out = plane * HW4;

    int hw = blockIdx.x * (TPB * ITER) + threadIdx.x;
#pragma unroll
    for (int it = 0; it < ITER; ++it, hw += TPB) {
        const f32x4 a = __builtin_nontemporal_load(&X[base_in + 0 * CHW4 + hw]);
        const f32x4 b = __builtin_nontemporal_load(&X[base_in + 1 * CHW4 + hw]);
        const f32x4 e = __builtin_nontemporal_load(&X[base_in + 2 * CHW4 + hw]);
        const f32x4 d = __builtin_nontemporal_load(&X[base_in + 3 * CHW4 + hw]);
        f32x4 r;
        r.x = fmaf(d.x, w3, fmaf(e.x, w2, fmaf(b.x, w1, a.x * w0)));
        r.y = fmaf(d.y, w3, fmaf(e.y, w2, fmaf(b.y, w1, a.y * w0)));
        r.z = fmaf(d.z, w3, fmaf(e.z, w2, fmaf(b.z, w1, a.z * w0)));
        r.w = fmaf(d.w, w3, fmaf(e.w, w2, fmaf(b.w, w1, a.w * w0)));
        __builtin_nontemporal_store(r, &O[base_out + hw]);
    }
}

extern "C" void kernel_launch(void* const* d_in, const int* in_sizes, int n_in,
                              void* d_out, int out_size, void* d_ws, size_t ws_size,
                              hipStream_t stream) {
    const f32x4* X = (const f32x4*)d_in[0];
    const float* W = (const float*)d_in[1];
    f32x4*       O = (f32x4*)d_out;

    dim3 grid(HW4 / (TPB * ITER), PLANES);  // (18, 384)
    wsum_kernel<<<grid, TPB, 0, stream>>>(X, W, O);
}